// Round 3
// baseline (863.078 us; speedup 1.0000x reference)
//
#include <hip/hip_runtime.h>
#include <cstddef>

#define H 256
#define NHEADS 8
#define HD 32
#define LMAX 128
#define KSTRIDE 4368   // per-head LDS stride in bf16 elems: 128*34 + 16

typedef __attribute__((ext_vector_type(8))) short bf16x8;
typedef __attribute__((ext_vector_type(4))) float f32x4;

__device__ __forceinline__ float bflo(unsigned u) { u <<= 16; return __builtin_bit_cast(float, u); }
__device__ __forceinline__ float bfhi(unsigned u) { u &= 0xffff0000u; return __builtin_bit_cast(float, u); }
__device__ __forceinline__ float bf2f(unsigned short s) { unsigned u = ((unsigned)s) << 16; return __builtin_bit_cast(float, u); }
__device__ __forceinline__ unsigned short f2bf(float x) {
    unsigned u = __builtin_bit_cast(unsigned, x);
    u += 0x7fffu + ((u >> 16) & 1u);           // round-to-nearest-even
    return (unsigned short)(u >> 16);
}
__device__ __forceinline__ void gl_lds16(const void* g, void* l) {
    __builtin_amdgcn_global_load_lds(
        (const __attribute__((address_space(1))) void*)g,
        (__attribute__((address_space(3))) void*)l, 16, 0, 0);
}

// ---------------------------------------------------------------------------
// K1: exclusive prefix sums of lens + zero stats
// ---------------------------------------------------------------------------
__global__ __launch_bounds__(512) void scan_zero_kernel(
    const int* __restrict__ slen, const int* __restrict__ dlen,
    int* __restrict__ soff, int* __restrict__ doff,
    float* __restrict__ stats, int B)
{
    __shared__ int ss[512], dd[512];
    const int t = threadIdx.x;
    const int sv = (t < B) ? slen[t] : 0;
    const int dv = (t < B) ? dlen[t] : 0;
    ss[t] = sv; dd[t] = dv;
    __syncthreads();
    for (int o = 1; o < 512; o <<= 1) {
        int a = (t >= o) ? ss[t - o] : 0;
        int b = (t >= o) ? dd[t - o] : 0;
        __syncthreads();
        ss[t] += a; dd[t] += b;
        __syncthreads();
    }
    if (t < B) { soff[t] = ss[t] - sv; doff[t] = dd[t] - dv; }
    stats[t] = 0.f;
    stats[t + 512] = 0.f;
}

// ---------------------------------------------------------------------------
// cvt: f32 -> bf16, float4-wide
// ---------------------------------------------------------------------------
__global__ __launch_bounds__(256) void cvt_bf16_kernel(
    const float* __restrict__ in, unsigned short* __restrict__ out, int n4)
{
    const int i = blockIdx.x * 256 + threadIdx.x;
    if (i >= n4) return;
    const float4 v = ((const float4*)in)[i];
    ushort4 o;
    o.x = f2bf(v.x); o.y = f2bf(v.y); o.z = f2bf(v.z); o.w = f2bf(v.w);
    ((ushort4*)out)[i] = o;
}

// ---------------------------------------------------------------------------
// K2: attention — one block per GRAPH (all 8 heads). 256 threads (4 waves).
// Wave w handles heads {2w, 2w+1}, loops all dst rows in pairs.
// K staged as bf16 per-head tiles [m][d] with stride 34 (2-way conflicts = free).
// Coalesced float4 staging reads; direct bf16 output (same-L2 write merge).
// ---------------------------------------------------------------------------
__global__ __launch_bounds__(256) void attn_kernel(
    const float* __restrict__ src, const float* __restrict__ dst,
    const int* __restrict__ soff, const int* __restrict__ doff,
    const int* __restrict__ slen, const int* __restrict__ dlen,
    unsigned short* __restrict__ hmsg_bf)
{
    const int b = blockIdx.x;
    const int Ls = slen[b], Ld = dlen[b];
    const int so = soff[b], df = doff[b];
    const int tid = threadIdx.x;
    const int w = tid >> 6, lane = tid & 63;

    __shared__ unsigned short Kh[NHEADS * KSTRIDE];
    __shared__ float2 pp[4][LMAX];

    // stage: float4 per thread -> 4 features (same d, heads h0..h0+3)
    const int iters = (Ls * H) >> 10;          // Ls/4
    for (int it = 0; it < iters; ++it) {
        const int idx = tid * 4 + (it << 10);
        const int m = idx >> 8, f = idx & 255;
        const int h0 = f & 7, dv = f >> 3;
        const float4 v = *(const float4*)&src[(size_t)(so + m) * H + f];
        Kh[(h0 + 0) * KSTRIDE + m * 34 + dv] = f2bf(v.x);
        Kh[(h0 + 1) * KSTRIDE + m * 34 + dv] = f2bf(v.y);
        Kh[(h0 + 2) * KSTRIDE + m * 34 + dv] = f2bf(v.z);
        Kh[(h0 + 3) * KSTRIDE + m * 34 + dv] = f2bf(v.w);
    }
    __syncthreads();   // only block barrier

    const float iscale = 0.17677669529663687f; // 1/sqrt(32)
    const int mA = min(lane, Ls - 1);
    const int mB = min(lane + 64, Ls - 1);
    const bool vA = lane < Ls;
    const bool vB = (lane + 64) < Ls;
    const int d = lane & 31, c = lane >> 5;

    for (int hi = 0; hi < 2; ++hi) {
        const int h = 2 * w + hi;
        const unsigned short* Kp = &Kh[h * KSTRIDE];
        const unsigned* KA = (const unsigned*)(Kp + mA * 34);
        const unsigned* KB = (const unsigned*)(Kp + mB * 34);

        for (int n0 = 0; n0 < Ld; n0 += 2) {
            const float* __restrict__ q0p = dst + (size_t)(df + n0) * H + h;
            const float* __restrict__ q1p = q0p + H;

            float a0 = 0.f, a1 = 0.f, b0 = 0.f, b1 = 0.f;
            #pragma unroll
            for (int dd = 0; dd < 16; ++dd) {
                const unsigned ka = KA[dd];
                const unsigned kb = KB[dd];
                const float kA0 = bflo(ka), kA1 = bfhi(ka);
                const float kB0 = bflo(kb), kB1 = bfhi(kb);
                const float q00 = q0p[dd * 16], q01 = q0p[dd * 16 + 8];
                const float q10 = q1p[dd * 16], q11 = q1p[dd * 16 + 8];
                a0 += q00 * kA0 + q01 * kA1;  a1 += q10 * kA0 + q11 * kA1;
                b0 += q00 * kB0 + q01 * kB1;  b1 += q10 * kB0 + q11 * kB1;
            }
            float sA0 = vA ? a0 * iscale : -INFINITY;
            float sA1 = vA ? a1 * iscale : -INFINITY;
            float sB0 = vB ? b0 * iscale : -INFINITY;
            float sB1 = vB ? b1 * iscale : -INFINITY;

            float mx0 = fmaxf(sA0, sB0), mx1 = fmaxf(sA1, sB1);
            #pragma unroll
            for (int o = 32; o > 0; o >>= 1) {
                mx0 = fmaxf(mx0, __shfl_xor(mx0, o));
                mx1 = fmaxf(mx1, __shfl_xor(mx1, o));
            }
            const float eA0 = __expf(sA0 - mx0), eA1 = __expf(sA1 - mx1);
            const float eB0 = __expf(sB0 - mx0), eB1 = __expf(sB1 - mx1);
            float sm0 = eA0 + eB0, sm1 = eA1 + eB1;
            #pragma unroll
            for (int o = 32; o > 0; o >>= 1) {
                sm0 += __shfl_xor(sm0, o);
                sm1 += __shfl_xor(sm1, o);
            }
            const float r0 = 1.f / sm0, r1 = 1.f / sm1;

            pp[w][lane]      = make_float2(eA0, eA1);
            pp[w][lane + 64] = make_float2(eB0, eB1);
            __asm__ volatile("" ::: "memory");
            __builtin_amdgcn_wave_barrier();

            float o0 = 0.f, o1 = 0.f;
            for (int m = c; m < Ls; m += 2) {
                const float kv = bf2f(Kp[m * 34 + d]);
                const float2 pv = pp[w][m];
                o0 += pv.x * kv;
                o1 += pv.y * kv;
            }
            __asm__ volatile("" ::: "memory");
            __builtin_amdgcn_wave_barrier();
            o0 += __shfl_xor(o0, 32);
            o1 += __shfl_xor(o1, 32);

            const int nst = n0 + c;            // Ld even -> always valid
            const float ov = c ? (o1 * r1) : (o0 * r0);
            hmsg_bf[(size_t)(df + nst) * H + d * NHEADS + h] = f2bf(ov);
        }
    }
}

// ---------------------------------------------------------------------------
// K3: GEMM1 (MFMA bf16): y1 = [A0|A1] @ W1^T + b1.  128x128 tile, BK=32.
// ---------------------------------------------------------------------------
__global__ __launch_bounds__(256) void gemm1_mfma(
    const unsigned short* __restrict__ A0, const unsigned short* __restrict__ A1,
    const unsigned short* __restrict__ W, const float* __restrict__ bias,
    float* __restrict__ out)
{
    __shared__ unsigned short Abuf[8 * 512];   // 8 subtiles x (16 rows x 32 k), fragment-ordered
    __shared__ unsigned short Bbuf[8 * 512];
    const int tid = threadIdx.x;
    const int w = tid >> 6, lane = tid & 63;
    const int rowBase = blockIdx.y * 128, colBase = blockIdx.x * 128;
    const int lr = lane & 15, lq = lane >> 4;
    const int wm = w >> 1, wn = w & 1;

    f32x4 acc[4][4];
    #pragma unroll
    for (int i = 0; i < 4; ++i)
        #pragma unroll
        for (int j = 0; j < 4; ++j) { f32x4 z = {0.f, 0.f, 0.f, 0.f}; acc[i][j] = z; }

    #pragma unroll
    for (int phase = 0; phase < 2; ++phase) {
        const unsigned short* __restrict__ Ap = phase ? A1 : A0;
        const int wOff = phase * 256;
        for (int kb = 0; kb < 256; kb += 32) {
            #pragma unroll
            for (int s = 0; s < 2; ++s) {
                const int sub = 2 * w + s;
                const unsigned short* ga = Ap + (size_t)(rowBase + sub * 16 + lr) * 256 + kb + lq * 8;
                gl_lds16(ga, &Abuf[sub * 512]);
                const unsigned short* gb = W + (size_t)(colBase + sub * 16 + lr) * 512 + wOff + kb + lq * 8;
                gl_lds16(gb, &Bbuf[sub * 512]);
            }
            __syncthreads();
            bf16x8 af[4], bf[4];
            #pragma unroll
            for (int i = 0; i < 4; ++i) af[i] = *(const bf16x8*)&Abuf[(wm * 4 + i) * 512 + lane * 8];
            #pragma unroll
            for (int j = 0; j < 4; ++j) bf[j] = *(const bf16x8*)&Bbuf[(wn * 4 + j) * 512 + lane * 8];
            #pragma unroll
            for (int i = 0; i < 4; ++i)
                #pragma unroll
                for (int j = 0; j < 4; ++j)
                    acc[i][j] = __builtin_amdgcn_mfma_f32_16x16x32_bf16(af[i], bf[j], acc[i][j], 0, 0, 0);
            __syncthreads();
        }
    }
    const int col0 = colBase + wn * 64;
    #pragma unroll
    for (int j = 0; j < 4; ++j) {
        const int col = col0 + j * 16 + lr;
        const float bv = bias[col];
        #pragma unroll
        for (int i = 0; i < 4; ++i) {
            const int row0 = rowBase + wm * 64 + i * 16 + lq * 4;
            #pragma unroll
            for (int r = 0; r < 4; ++r)
                out[(size_t)(row0 + r) * 256 + col] = acc[i][j][r] + bv;
        }
    }
}

// ---------------------------------------------------------------------------
// K5: GEMM2 (MFMA bf16): y2 = A2 @ W2^T + b2.  K=256.
// ---------------------------------------------------------------------------
__global__ __launch_bounds__(256) void gemm2_mfma(
    const unsigned short* __restrict__ A2,
    const unsigned short* __restrict__ W, const float* __restrict__ bias,
    float* __restrict__ out)
{
    __shared__ unsigned short Abuf[8 * 512];
    __shared__ unsigned short Bbuf[8 * 512];
    const int tid = threadIdx.x;
    const int w = tid >> 6, lane = tid & 63;
    const int rowBase = blockIdx.y * 128, colBase = blockIdx.x * 128;
    const int lr = lane & 15, lq = lane >> 4;
    const int wm = w >> 1, wn = w & 1;

    f32x4 acc[4][4];
    #pragma unroll
    for (int i = 0; i < 4; ++i)
        #pragma unroll
        for (int j = 0; j < 4; ++j) { f32x4 z = {0.f, 0.f, 0.f, 0.f}; acc[i][j] = z; }

    for (int kb = 0; kb < 256; kb += 32) {
        #pragma unroll
        for (int s = 0; s < 2; ++s) {
            const int sub = 2 * w + s;
            const unsigned short* ga = A2 + (size_t)(rowBase + sub * 16 + lr) * 256 + kb + lq * 8;
            gl_lds16(ga, &Abuf[sub * 512]);
            const unsigned short* gb = W + (size_t)(colBase + sub * 16 + lr) * 256 + kb + lq * 8;
            gl_lds16(gb, &Bbuf[sub * 512]);
        }
        __syncthreads();
        bf16x8 af[4], bf[4];
        #pragma unroll
        for (int i = 0; i < 4; ++i) af[i] = *(const bf16x8*)&Abuf[(wm * 4 + i) * 512 + lane * 8];
        #pragma unroll
        for (int j = 0; j < 4; ++j) bf[j] = *(const bf16x8*)&Bbuf[(wn * 4 + j) * 512 + lane * 8];
        #pragma unroll
        for (int i = 0; i < 4; ++i)
            #pragma unroll
            for (int j = 0; j < 4; ++j)
                acc[i][j] = __builtin_amdgcn_mfma_f32_16x16x32_bf16(af[i], bf[j], acc[i][j], 0, 0, 0);
        __syncthreads();
    }
    const int col0 = colBase + wn * 64;
    #pragma unroll
    for (int j = 0; j < 4; ++j) {
        const int col = col0 + j * 16 + lr;
        const float bv = bias[col];
        #pragma unroll
        for (int i = 0; i < 4; ++i) {
            const int row0 = rowBase + wm * 64 + i * 16 + lq * 4;
            #pragma unroll
            for (int r = 0; r < 4; ++r)
                out[(size_t)(row0 + r) * 256 + col] = acc[i][j][r] + bv;
        }
    }
}

// ---------------------------------------------------------------------------
// K4/K6: per-column sum & sumsq over 64-row chunks; atomic into stats.
// ---------------------------------------------------------------------------
__global__ __launch_bounds__(256) void colstats_kernel(
    const float* __restrict__ y, float* __restrict__ sum, float* __restrict__ sq,
    int Nrows)
{
    const int c = threadIdx.x;
    const int r0 = blockIdx.x * 64;
    const int r1 = min(r0 + 64, Nrows);
    float s = 0.f, q = 0.f;
    for (int r = r0; r < r1; r++) {
        const float v = y[(size_t)r * 256 + c];
        s += v; q += v * v;
    }
    atomicAdd(&sum[c], s);
    atomicAdd(&sq[c], q);
}

__global__ __launch_bounds__(256) void finalize_kernel(
    const float* __restrict__ sum, const float* __restrict__ sq,
    const float* __restrict__ gamma, const float* __restrict__ beta,
    float* __restrict__ scale, float* __restrict__ shift, int Nrows)
{
    const int c = threadIdx.x;
    const float invN = 1.0f / (float)Nrows;
    const float mean = sum[c] * invN;
    const float var  = sq[c] * invN - mean * mean;
    const float rstd = rsqrtf(var + 1e-5f);
    const float sc   = gamma[c] * rstd;
    scale[c] = sc;
    shift[c] = beta[c] - mean * sc;
}

// ---------------------------------------------------------------------------
// bn_relu_cast: a2 = bf16(relu(y1*scale1 + shift1))
// ---------------------------------------------------------------------------
__global__ __launch_bounds__(256) void bnrelu_cast_kernel(
    const float* __restrict__ y1,
    const float* __restrict__ scale, const float* __restrict__ shift,
    unsigned short* __restrict__ out, int n4)
{
    const int i = blockIdx.x * 256 + threadIdx.x;
    if (i >= n4) return;
    const int j0 = (i & 63) * 4;
    const float4 v = ((const float4*)y1)[i];
    const float4 s = *(const float4*)&scale[j0];
    const float4 t = *(const float4*)&shift[j0];
    ushort4 o;
    o.x = f2bf(fmaxf(v.x * s.x + t.x, 0.f));
    o.y = f2bf(fmaxf(v.y * s.y + t.y, 0.f));
    o.z = f2bf(fmaxf(v.z * s.z + t.z, 0.f));
    o.w = f2bf(fmaxf(v.w * s.w + t.w, 0.f));
    ((ushort4*)out)[i] = o;
}

// ---------------------------------------------------------------------------
// K7: out = dst_h + y2*scale2 + shift2
// ---------------------------------------------------------------------------
__global__ __launch_bounds__(256) void epilogue_kernel(
    const float* __restrict__ dst, const float* __restrict__ y2,
    const float* __restrict__ scale2, const float* __restrict__ shift2,
    float* __restrict__ out, int total4)
{
    const int i = blockIdx.x * 256 + threadIdx.x;
    if (i >= total4) return;
    const float4 d = ((const float4*)dst)[i];
    const float4 v = ((const float4*)y2)[i];
    const int j0 = (i & 63) * 4;
    const float4 s = *(const float4*)&scale2[j0];
    const float4 t = *(const float4*)&shift2[j0];
    float4 o;
    o.x = d.x + v.x * s.x + t.x;
    o.y = d.y + v.y * s.y + t.y;
    o.z = d.z + v.z * s.z + t.z;
    o.w = d.w + v.w * s.w + t.w;
    ((float4*)out)[i] = o;
}

// ---------------------------------------------------------------------------
extern "C" void kernel_launch(void* const* d_in, const int* in_sizes, int n_in,
                              void* d_out, int out_size, void* d_ws, size_t ws_size,
                              hipStream_t stream)
{
    const float* src_h  = (const float*)d_in[0];
    const float* dst_h  = (const float*)d_in[1];
    const int*   slen   = (const int*)d_in[2];
    const int*   dlen   = (const int*)d_in[3];
    const float* W1     = (const float*)d_in[4];
    const float* b1     = (const float*)d_in[5];
    const float* gamma1 = (const float*)d_in[6];
    const float* beta1  = (const float*)d_in[7];
    const float* W2     = (const float*)d_in[8];
    const float* b2     = (const float*)d_in[9];
    const float* gamma2 = (const float*)d_in[10];
    const float* beta2  = (const float*)d_in[11];
    float* out = (float*)d_out;

    const int N = in_sizes[1] / H;     // 40960 rows
    const int B = in_sizes[2];         // 512 graphs

    // workspace layout (float offsets)
    float* ws     = (float*)d_ws;
    int*   soff   = (int*)d_ws;                       // 512 ints
    int*   doff   = soff + 512;                       // 512 ints
    float* stats  = ws + 1024;                        // 1024 floats
    float* scale1 = ws + 2048;
    float* shift1 = ws + 2304;
    float* scale2 = ws + 2560;
    float* shift2 = ws + 2816;
    const size_t nbf = (size_t)N * H / 2;             // bf16 matrix size in floats
    unsigned short* A0bf   = (unsigned short*)(ws + 4096);
    unsigned short* hmsgbf = (unsigned short*)(ws + 4096 + nbf);      // also a2 later
    unsigned short* W1bf   = (unsigned short*)(ws + 4096 + 2 * nbf);
    unsigned short* W2bf   = (unsigned short*)(ws + 4096 + 2 * nbf + 65536);
    float* y1 = ws + 4096 + 2 * nbf + 65536 + 32768;  // also y2 later
    float* y2 = y1;

    scan_zero_kernel<<<1, 512, 0, stream>>>(slen, dlen, soff, doff, stats, B);

    const int n4 = N * H / 4;
    cvt_bf16_kernel<<<(n4 + 255) / 256, 256, 0, stream>>>(dst_h, A0bf, n4);
    cvt_bf16_kernel<<<(131072 / 4 + 255) / 256, 256, 0, stream>>>(W1, W1bf, 131072 / 4);
    cvt_bf16_kernel<<<(65536 / 4 + 255) / 256, 256, 0, stream>>>(W2, W2bf, 65536 / 4);

    attn_kernel<<<B, 256, 0, stream>>>(src_h, dst_h, soff, doff, slen, dlen, hmsgbf);

    dim3 ggrid(H / 128, N / 128);     // (2, 320)
    gemm1_mfma<<<ggrid, 256, 0, stream>>>(A0bf, hmsgbf, W1bf, b1, y1);
    colstats_kernel<<<N / 64, 256, 0, stream>>>(y1, stats + 0, stats + 256, N);
    finalize_kernel<<<1, 256, 0, stream>>>(stats + 0, stats + 256, gamma1, beta1, scale1, shift1, N);

    bnrelu_cast_kernel<<<(n4 + 255) / 256, 256, 0, stream>>>(y1, scale1, shift1, hmsgbf, n4);

    gemm2_mfma<<<ggrid, 256, 0, stream>>>(hmsgbf, W2bf, b2, y2);
    colstats_kernel<<<N / 64, 256, 0, stream>>>(y2, stats + 512, stats + 768, N);
    finalize_kernel<<<1, 256, 0, stream>>>(stats + 512, stats + 768, gamma2, beta2, scale2, shift2, N);

    epilogue_kernel<<<(n4 + 255) / 256, 256, 0, stream>>>(dst_h, y2, scale2, shift2, out, n4);
}

// Round 4
// 344.324 us; speedup vs baseline: 2.5066x; 2.5066x over previous
//
#include <hip/hip_runtime.h>
#include <cstddef>

#define H 256
#define NHEADS 8
#define HD 32

typedef __attribute__((ext_vector_type(8))) short bf16x8;
typedef __attribute__((ext_vector_type(4))) float f32x4;

__device__ __forceinline__ unsigned short f2bf(float x) {
    unsigned u = __builtin_bit_cast(unsigned, x);
    u += 0x7fffu + ((u >> 16) & 1u);           // round-to-nearest-even
    return (unsigned short)(u >> 16);
}
__device__ __forceinline__ void gl_lds16(const void* g, void* l) {
    __builtin_amdgcn_global_load_lds(
        (const __attribute__((address_space(1))) void*)g,
        (__attribute__((address_space(3))) void*)l, 16, 0, 0);
}

// ---------------------------------------------------------------------------
// K1: exclusive prefix sums of lens + zero stats
// ---------------------------------------------------------------------------
__global__ __launch_bounds__(512) void scan_zero_kernel(
    const int* __restrict__ slen, const int* __restrict__ dlen,
    int* __restrict__ soff, int* __restrict__ doff,
    float* __restrict__ stats, int B)
{
    __shared__ int ss[512], dd[512];
    const int t = threadIdx.x;
    const int sv = (t < B) ? slen[t] : 0;
    const int dv = (t < B) ? dlen[t] : 0;
    ss[t] = sv; dd[t] = dv;
    __syncthreads();
    for (int o = 1; o < 512; o <<= 1) {
        int a = (t >= o) ? ss[t - o] : 0;
        int b = (t >= o) ? dd[t - o] : 0;
        __syncthreads();
        ss[t] += a; dd[t] += b;
        __syncthreads();
    }
    if (t < B) { soff[t] = ss[t] - sv; doff[t] = dd[t] - dv; }
    stats[t] = 0.f;
    stats[t + 512] = 0.f;
}

// ---------------------------------------------------------------------------
// prepass: [N,256] f32 (f = d*8+h) -> per-head bf16 planes T[h][n][32];
// optionally also d-major V2[h][32][n]. 64 rows per block, LDS-tiled.
// ---------------------------------------------------------------------------
__global__ __launch_bounds__(256) void prepass_kernel(
    const float* __restrict__ in, unsigned short* __restrict__ T,
    unsigned short* __restrict__ V2, int N)
{
    __shared__ unsigned short pl[8 * 64 * 40];   // [h][row][d], stride 40
    const int t = threadIdx.x;
    const int rb = blockIdx.x * 64;
    #pragma unroll
    for (int i = 0; i < 16; ++i) {
        const int idx = t + i * 256;             // 4096 float4s
        const int row = idx >> 6, f4 = idx & 63;
        const float4 v = ((const float4*)in)[(size_t)(rb + row) * 64 + f4];
        const int f0 = f4 * 4, h0 = f0 & 7, d = f0 >> 3;
        pl[(h0 + 0) * 2560 + row * 40 + d] = f2bf(v.x);
        pl[(h0 + 1) * 2560 + row * 40 + d] = f2bf(v.y);
        pl[(h0 + 2) * 2560 + row * 40 + d] = f2bf(v.z);
        pl[(h0 + 3) * 2560 + row * 40 + d] = f2bf(v.w);
    }
    __syncthreads();
    #pragma unroll
    for (int i = 0; i < 8; ++i) {
        const int idx = t + i * 256;             // 2048 16B chunks
        const int h = idx >> 8, rem = idx & 255, row = rem >> 2, c = rem & 3;
        const bf16x8 val = *(const bf16x8*)&pl[h * 2560 + row * 40 + c * 8];
        *(bf16x8*)&T[(size_t)(h * N + rb + row) * 32 + c * 8] = val;
    }
    if (V2) {
        #pragma unroll
        for (int i = 0; i < 8; ++i) {
            const int idx = t + i * 256;         // 8 planes x 32 d x 8 n-chunks
            const int h = idx >> 8, rem = idx & 255, d = rem >> 3, nc = rem & 7;
            unsigned short tmp[8];
            #pragma unroll
            for (int j = 0; j < 8; ++j) tmp[j] = pl[h * 2560 + (nc * 8 + j) * 40 + d];
            ushort4 lo, hi;
            lo.x = tmp[0]; lo.y = tmp[1]; lo.z = tmp[2]; lo.w = tmp[3];
            hi.x = tmp[4]; hi.y = tmp[5]; hi.z = tmp[6]; hi.w = tmp[7];
            *(ushort4*)&V2[(size_t)(h * 32 + d) * N + rb + nc * 8] = lo;
            *(ushort4*)&V2[(size_t)(h * 32 + d) * N + rb + nc * 8 + 4] = hi;
        }
    }
}

// ---------------------------------------------------------------------------
// W1 cvt with K-dim permutation: W1p[c][half*256 + h*32 + d] = W1[c][half*256 + d*8 + h]
// ---------------------------------------------------------------------------
__global__ __launch_bounds__(256) void cvtW1_perm_kernel(
    const float* __restrict__ W1, unsigned short* __restrict__ W1p)
{
    const int idx = blockIdx.x * 256 + threadIdx.x;   // 131072 elems
    const int kp = idx & 511, c = idx >> 9;
    const int half = kp >> 8, r = kp & 255, h = r >> 5, d = r & 31;
    W1p[(size_t)c * 512 + kp] = f2bf(W1[(size_t)c * 512 + half * 256 + d * 8 + h]);
}

__global__ __launch_bounds__(256) void cvt_bf16_kernel(
    const float* __restrict__ in, unsigned short* __restrict__ out, int n4)
{
    const int i = blockIdx.x * 256 + threadIdx.x;
    if (i >= n4) return;
    const float4 v = ((const float4*)in)[i];
    ushort4 o;
    o.x = f2bf(v.x); o.y = f2bf(v.y); o.z = f2bf(v.z); o.w = f2bf(v.w);
    ((ushort4*)out)[i] = o;
}

// ---------------------------------------------------------------------------
// K2: MFMA attention. One wave per (graph, head). S^T = K*Q^T via mfma
// (A=K rows m, B=Q rows n); softmax over m in-lane + shfl_xor(16,32);
// P^T -> per-wave LDS [n][m] bf16; PV via mfma(P-frag, V-frag from VT2).
// ---------------------------------------------------------------------------
template<int LS>
__device__ __forceinline__ void attn_body(
    const unsigned short* __restrict__ KT, const unsigned short* __restrict__ QT,
    const unsigned short* __restrict__ VT2, unsigned short* __restrict__ OT,
    unsigned short* __restrict__ Ps, int N, int so, int df, int Ld, int h, int lane)
{
    constexpr int MT = LS / 16, CH = LS / 32;
    const int lr = lane & 15, lq = lane >> 4;
    const float iscale = 0.17677669529663687f;  // 1/sqrt(32)

    bf16x8 kf[MT];
    #pragma unroll
    for (int mt = 0; mt < MT; ++mt)
        kf[mt] = *(const bf16x8*)&KT[(size_t)(h * N + so + mt * 16 + lr) * 32 + lq * 8];
    bf16x8 vf[CH][2];
    #pragma unroll
    for (int c = 0; c < CH; ++c)
        #pragma unroll
        for (int dt = 0; dt < 2; ++dt)
            vf[c][dt] = *(const bf16x8*)&VT2[(size_t)(h * 32 + dt * 16 + lr) * N + so + c * 32 + lq * 8];

    const int NT = Ld >> 4;
    for (int nt = 0; nt < NT; ++nt) {
        const bf16x8 qf = *(const bf16x8*)&QT[(size_t)(h * N + df + nt * 16 + lr) * 32 + lq * 8];
        f32x4 s[MT];
        #pragma unroll
        for (int mt = 0; mt < MT; ++mt) {
            f32x4 z = {0.f, 0.f, 0.f, 0.f};
            s[mt] = __builtin_amdgcn_mfma_f32_16x16x32_bf16(kf[mt], qf, z, 0, 0, 0);
        }
        // max over m for col n = lr
        float mx = -INFINITY;
        #pragma unroll
        for (int mt = 0; mt < MT; ++mt)
            mx = fmaxf(mx, fmaxf(fmaxf(s[mt][0], s[mt][1]), fmaxf(s[mt][2], s[mt][3])));
        mx = fmaxf(mx, __shfl_xor(mx, 16));
        mx = fmaxf(mx, __shfl_xor(mx, 32));
        const float mxi = mx * iscale;
        float sum = 0.f;
        #pragma unroll
        for (int mt = 0; mt < MT; ++mt) {
            #pragma unroll
            for (int r = 0; r < 4; ++r) {
                const float e = __expf(s[mt][r] * iscale - mxi);
                s[mt][r] = e; sum += e;
            }
        }
        sum += __shfl_xor(sum, 16);
        sum += __shfl_xor(sum, 32);
        const float rinv = 1.f / sum;
        // P^T -> LDS [n=lr][m = mt*16 + lq*4 + r]
        #pragma unroll
        for (int mt = 0; mt < MT; ++mt) {
            uint2 p;
            p.x = ((unsigned)f2bf(s[mt][0])) | (((unsigned)f2bf(s[mt][1])) << 16);
            p.y = ((unsigned)f2bf(s[mt][2])) | (((unsigned)f2bf(s[mt][3])) << 16);
            *(uint2*)&Ps[lr * 136 + mt * 16 + lq * 4] = p;
        }
        __asm__ volatile("" ::: "memory");
        __builtin_amdgcn_wave_barrier();
        f32x4 o0 = {0.f, 0.f, 0.f, 0.f}, o1 = {0.f, 0.f, 0.f, 0.f};
        #pragma unroll
        for (int c = 0; c < CH; ++c) {
            const bf16x8 pa = *(const bf16x8*)&Ps[lr * 136 + c * 32 + lq * 8];
            o0 = __builtin_amdgcn_mfma_f32_16x16x32_bf16(pa, vf[c][0], o0, 0, 0, 0);
            o1 = __builtin_amdgcn_mfma_f32_16x16x32_bf16(pa, vf[c][1], o1, 0, 0, 0);
        }
        __asm__ volatile("" ::: "memory");
        __builtin_amdgcn_wave_barrier();
        // normalize + store: O rows n = lq*4+r, cols d = lr (+16)
        #pragma unroll
        for (int r = 0; r < 4; ++r) {
            const float rv = __shfl(rinv, lq * 4 + r);
            const int row = df + nt * 16 + lq * 4 + r;
            OT[(size_t)(h * N + row) * 32 + lr]      = f2bf(o0[r] * rv);
            OT[(size_t)(h * N + row) * 32 + 16 + lr] = f2bf(o1[r] * rv);
        }
    }
}

__global__ __launch_bounds__(256) void attn_mfma(
    const unsigned short* __restrict__ KT, const unsigned short* __restrict__ QT,
    const unsigned short* __restrict__ VT2, unsigned short* __restrict__ OT,
    const int* __restrict__ soff, const int* __restrict__ doff,
    const int* __restrict__ slen, const int* __restrict__ dlen, int N)
{
    __shared__ unsigned short Ps[4][16 * 136];
    const int b = blockIdx.x >> 1, half = blockIdx.x & 1;
    const int w = threadIdx.x >> 6, lane = threadIdx.x & 63;
    const int h = half * 4 + w;
    const int Ls = slen[b], Ld = dlen[b], so = soff[b], df = doff[b];
    switch (Ls) {
        case 32:  attn_body<32> (KT, QT, VT2, OT, Ps[w], N, so, df, Ld, h, lane); break;
        case 64:  attn_body<64> (KT, QT, VT2, OT, Ps[w], N, so, df, Ld, h, lane); break;
        case 96:  attn_body<96> (KT, QT, VT2, OT, Ps[w], N, so, df, Ld, h, lane); break;
        default:  attn_body<128>(KT, QT, VT2, OT, Ps[w], N, so, df, Ld, h, lane); break;
    }
}

// ---------------------------------------------------------------------------
// K3: GEMM1 (MFMA bf16): y1 = [QT | OT](per-head K order) @ W1p^T + b1.
// ---------------------------------------------------------------------------
__global__ __launch_bounds__(256) void gemm1_mfma(
    const unsigned short* __restrict__ QT, const unsigned short* __restrict__ OT,
    const unsigned short* __restrict__ W, const float* __restrict__ bias,
    float* __restrict__ out, int N)
{
    __shared__ unsigned short Abuf[8 * 512];
    __shared__ unsigned short Bbuf[8 * 512];
    const int tid = threadIdx.x;
    const int w = tid >> 6, lane = tid & 63;
    const int rowBase = blockIdx.y * 128, colBase = blockIdx.x * 128;
    const int lr = lane & 15, lq = lane >> 4;
    const int wm = w >> 1, wn = w & 1;

    f32x4 acc[4][4];
    #pragma unroll
    for (int i = 0; i < 4; ++i)
        #pragma unroll
        for (int j = 0; j < 4; ++j) { f32x4 z = {0.f, 0.f, 0.f, 0.f}; acc[i][j] = z; }

    #pragma unroll
    for (int phase = 0; phase < 2; ++phase) {
        const unsigned short* __restrict__ Ap = phase ? OT : QT;
        const int wOff = phase * 256;
        for (int kb = 0; kb < 256; kb += 32) {
            const int hh = (kb >> 5) + (lq >> 2);
            const int dd = (lq & 3) * 8;
            #pragma unroll
            for (int s = 0; s < 2; ++s) {
                const int sub = 2 * w + s;
                const unsigned short* ga = Ap + (size_t)(hh * N + rowBase + sub * 16 + lr) * 32 + dd;
                gl_lds16(ga, &Abuf[sub * 512]);
                const unsigned short* gb = W + (size_t)(colBase + sub * 16 + lr) * 512 + wOff + kb + lq * 8;
                gl_lds16(gb, &Bbuf[sub * 512]);
            }
            __syncthreads();
            bf16x8 af[4], bf[4];
            #pragma unroll
            for (int i = 0; i < 4; ++i) af[i] = *(const bf16x8*)&Abuf[(wm * 4 + i) * 512 + lane * 8];
            #pragma unroll
            for (int j = 0; j < 4; ++j) bf[j] = *(const bf16x8*)&Bbuf[(wn * 4 + j) * 512 + lane * 8];
            #pragma unroll
            for (int i = 0; i < 4; ++i)
                #pragma unroll
                for (int j = 0; j < 4; ++j)
                    acc[i][j] = __builtin_amdgcn_mfma_f32_16x16x32_bf16(af[i], bf[j], acc[i][j], 0, 0, 0);
            __syncthreads();
        }
    }
    const int col0 = colBase + wn * 64;
    #pragma unroll
    for (int j = 0; j < 4; ++j) {
        const int col = col0 + j * 16 + lr;
        const float bv = bias[col];
        #pragma unroll
        for (int i = 0; i < 4; ++i) {
            const int row0 = rowBase + wm * 64 + i * 16 + lq * 4;
            #pragma unroll
            for (int r = 0; r < 4; ++r)
                out[(size_t)(row0 + r) * 256 + col] = acc[i][j][r] + bv;
        }
    }
}

// ---------------------------------------------------------------------------
// K5: GEMM2 (MFMA bf16): y2 = A2 @ W2^T + b2.
// ---------------------------------------------------------------------------
__global__ __launch_bounds__(256) void gemm2_mfma(
    const unsigned short* __restrict__ A2,
    const unsigned short* __restrict__ W, const float* __restrict__ bias,
    float* __restrict__ out)
{
    __shared__ unsigned short Abuf[8 * 512];
    __shared__ unsigned short Bbuf[8 * 512];
    const int tid = threadIdx.x;
    const int w = tid >> 6, lane = tid & 63;
    const int rowBase = blockIdx.y * 128, colBase = blockIdx.x * 128;
    const int lr = lane & 15, lq = lane >> 4;
    const int wm = w >> 1, wn = w & 1;

    f32x4 acc[4][4];
    #pragma unroll
    for (int i = 0; i < 4; ++i)
        #pragma unroll
        for (int j = 0; j < 4; ++j) { f32x4 z = {0.f, 0.f, 0.f, 0.f}; acc[i][j] = z; }

    for (int kb = 0; kb < 256; kb += 32) {
        #pragma unroll
        for (int s = 0; s < 2; ++s) {
            const int sub = 2 * w + s;
            const unsigned short* ga = A2 + (size_t)(rowBase + sub * 16 + lr) * 256 + kb + lq * 8;
            gl_lds16(ga, &Abuf[sub * 512]);
            const unsigned short* gb = W + (size_t)(colBase + sub * 16 + lr) * 256 + kb + lq * 8;
            gl_lds16(gb, &Bbuf[sub * 512]);
        }
        __syncthreads();
        bf16x8 af[4], bf[4];
        #pragma unroll
        for (int i = 0; i < 4; ++i) af[i] = *(const bf16x8*)&Abuf[(wm * 4 + i) * 512 + lane * 8];
        #pragma unroll
        for (int j = 0; j < 4; ++j) bf[j] = *(const bf16x8*)&Bbuf[(wn * 4 + j) * 512 + lane * 8];
        #pragma unroll
        for (int i = 0; i < 4; ++i)
            #pragma unroll
            for (int j = 0; j < 4; ++j)
                acc[i][j] = __builtin_amdgcn_mfma_f32_16x16x32_bf16(af[i], bf[j], acc[i][j], 0, 0, 0);
        __syncthreads();
    }
    const int col0 = colBase + wn * 64;
    #pragma unroll
    for (int j = 0; j < 4; ++j) {
        const int col = col0 + j * 16 + lr;
        const float bv = bias[col];
        #pragma unroll
        for (int i = 0; i < 4; ++i) {
            const int row0 = rowBase + wm * 64 + i * 16 + lq * 4;
            #pragma unroll
            for (int r = 0; r < 4; ++r)
                out[(size_t)(row0 + r) * 256 + col] = acc[i][j][r] + bv;
        }
    }
}

// ---------------------------------------------------------------------------
// colstats / finalize / bnrelu / epilogue
// ---------------------------------------------------------------------------
__global__ __launch_bounds__(256) void colstats_kernel(
    const float* __restrict__ y, float* __restrict__ sum, float* __restrict__ sq,
    int Nrows)
{
    const int c = threadIdx.x;
    const int r0 = blockIdx.x * 64;
    const int r1 = min(r0 + 64, Nrows);
    float s = 0.f, q = 0.f;
    for (int r = r0; r < r1; r++) {
        const float v = y[(size_t)r * 256 + c];
        s += v; q += v * v;
    }
    atomicAdd(&sum[c], s);
    atomicAdd(&sq[c], q);
}

__global__ __launch_bounds__(256) void finalize_kernel(
    const float* __restrict__ sum, const float* __restrict__ sq,
    const float* __restrict__ gamma, const float* __restrict__ beta,
    float* __restrict__ scale, float* __restrict__ shift, int Nrows)
{
    const int c = threadIdx.x;
    const float invN = 1.0f / (float)Nrows;
    const float mean = sum[c] * invN;
    const float var  = sq[c] * invN - mean * mean;
    const float rstd = rsqrtf(var + 1e-5f);
    const float sc   = gamma[c] * rstd;
    scale[c] = sc;
    shift[c] = beta[c] - mean * sc;
}

__global__ __launch_bounds__(256) void bnrelu_cast_kernel(
    const float* __restrict__ y1,
    const float* __restrict__ scale, const float* __restrict__ shift,
    unsigned short* __restrict__ out, int n4)
{
    const int i = blockIdx.x * 256 + threadIdx.x;
    if (i >= n4) return;
    const int j0 = (i & 63) * 4;
    const float4 v = ((const float4*)y1)[i];
    const float4 s = *(const float4*)&scale[j0];
    const float4 t = *(const float4*)&shift[j0];
    ushort4 o;
    o.x = f2bf(fmaxf(v.x * s.x + t.x, 0.f));
    o.y = f2bf(fmaxf(v.y * s.y + t.y, 0.f));
    o.z = f2bf(fmaxf(v.z * s.z + t.z, 0.f));
    o.w = f2bf(fmaxf(v.w * s.w + t.w, 0.f));
    ((ushort4*)out)[i] = o;
}

__global__ __launch_bounds__(256) void epilogue_kernel(
    const float* __restrict__ dst, const float* __restrict__ y2,
    const float* __restrict__ scale2, const float* __restrict__ shift2,
    float* __restrict__ out, int total4)
{
    const int i = blockIdx.x * 256 + threadIdx.x;
    if (i >= total4) return;
    const float4 d = ((const float4*)dst)[i];
    const float4 v = ((const float4*)y2)[i];
    const int j0 = (i & 63) * 4;
    const float4 s = *(const float4*)&scale2[j0];
    const float4 t = *(const float4*)&shift2[j0];
    float4 o;
    o.x = d.x + v.x * s.x + t.x;
    o.y = d.y + v.y * s.y + t.y;
    o.z = d.z + v.z * s.z + t.z;
    o.w = d.w + v.w * s.w + t.w;
    ((float4*)out)[i] = o;
}

// ---------------------------------------------------------------------------
extern "C" void kernel_launch(void* const* d_in, const int* in_sizes, int n_in,
                              void* d_out, int out_size, void* d_ws, size_t ws_size,
                              hipStream_t stream)
{
    const float* src_h  = (const float*)d_in[0];
    const float* dst_h  = (const float*)d_in[1];
    const int*   slen   = (const int*)d_in[2];
    const int*   dlen   = (const int*)d_in[3];
    const float* W1     = (const float*)d_in[4];
    const float* b1     = (const float*)d_in[5];
    const float* gamma1 = (const float*)d_in[6];
    const float* beta1  = (const float*)d_in[7];
    const float* W2     = (const float*)d_in[8];
    const float* b2     = (const float*)d_in[9];
    const float* gamma2 = (const float*)d_in[10];
    const float* beta2  = (const float*)d_in[11];
    float* out = (float*)d_out;

    const int N = in_sizes[1] / H;     // 40960
    const int B = in_sizes[2];         // 512

    // ---- workspace layout (bytes) ----
    char* base = (char*)d_ws;
    int*   soff   = (int*)(base + 0);            // 2KB
    int*   doff   = (int*)(base + 2048);         // 2KB
    float* stats  = (float*)(base + 4096);       // 4KB
    float* scale1 = (float*)(base + 8192);
    float* shift1 = (float*)(base + 8192 + 1024);
    float* scale2 = (float*)(base + 8192 + 2048);
    float* shift2 = (float*)(base + 8192 + 3072);
    unsigned short* W1p  = (unsigned short*)(base + 16384);            // 256KB
    unsigned short* W2bf = (unsigned short*)(base + 16384 + 262144);   // 128KB
    const size_t S = (size_t)N * H * sizeof(unsigned short);           // 21 MB
    char* big = base + (1 << 20);
    unsigned short* KT  = (unsigned short*)(big);
    unsigned short* VT2 = (unsigned short*)(big + S);
    unsigned short* QT  = (unsigned short*)(big + 2 * S);
    unsigned short* OT  = (unsigned short*)(big + 3 * S);
    float* y1 = (float*)(big);            // reuse KT+VT2 after attention
    unsigned short* a2 = QT;              // reuse QT after gemm1
    float* y2 = (float*)(big + 3 * S);    // reuse OT + tail after gemm1

    scan_zero_kernel<<<1, 512, 0, stream>>>(slen, dlen, soff, doff, stats, B);

    prepass_kernel<<<N / 64, 256, 0, stream>>>(src_h, KT, VT2, N);
    prepass_kernel<<<N / 64, 256, 0, stream>>>(dst_h, QT, (unsigned short*)nullptr, N);
    cvtW1_perm_kernel<<<512, 256, 0, stream>>>(W1, W1p);
    cvt_bf16_kernel<<<(65536 / 4 + 255) / 256, 256, 0, stream>>>(W2, W2bf, 65536 / 4);

    attn_mfma<<<B * 2, 256, 0, stream>>>(KT, QT, VT2, OT, soff, doff, slen, dlen, N);

    dim3 ggrid(H / 128, N / 128);     // (2, 320)
    gemm1_mfma<<<ggrid, 256, 0, stream>>>(QT, OT, W1p, b1, y1, N);
    colstats_kernel<<<N / 64, 256, 0, stream>>>(y1, stats + 0, stats + 256, N);
    finalize_kernel<<<1, 256, 0, stream>>>(stats + 0, stats + 256, gamma1, beta1, scale1, shift1, N);

    const int n4 = N * H / 4;
    bnrelu_cast_kernel<<<(n4 + 255) / 256, 256, 0, stream>>>(y1, scale1, shift1, a2, n4);

    gemm2_mfma<<<ggrid, 256, 0, stream>>>(a2, W2bf, b2, y2);
    colstats_kernel<<<N / 64, 256, 0, stream>>>(y2, stats + 512, stats + 768, N);
    finalize_kernel<<<1, 256, 0, stream>>>(stats + 512, stats + 768, gamma2, beta2, scale2, shift2, N);

    epilogue_kernel<<<(n4 + 255) / 256, 256, 0, stream>>>(dst_h, y2, scale2, shift2, out, n4);
}

// Round 5
// 283.552 us; speedup vs baseline: 3.0438x; 1.2143x over previous
//
#include <hip/hip_runtime.h>
#include <cstddef>

#define H 256
#define NHEADS 8
#define HD 32

typedef __attribute__((ext_vector_type(8))) short bf16x8;
typedef __attribute__((ext_vector_type(4))) float f32x4;

__device__ __forceinline__ float bf2f(unsigned short s) {
    unsigned u = ((unsigned)s) << 16; return __builtin_bit_cast(float, u);
}
__device__ __forceinline__ float bfe2f(short s) {
    unsigned u = ((unsigned)(unsigned short)s) << 16; return __builtin_bit_cast(float, u);
}
__device__ __forceinline__ unsigned short f2bf(float x) {
    unsigned u = __builtin_bit_cast(unsigned, x);
    u += 0x7fffu + ((u >> 16) & 1u);           // round-to-nearest-even
    return (unsigned short)(u >> 16);
}
__device__ __forceinline__ void gl_lds16(const void* g, void* l) {
    __builtin_amdgcn_global_load_lds(
        (const __attribute__((address_space(1))) void*)g,
        (__attribute__((address_space(3))) void*)l, 16, 0, 0);
}

// ---------------------------------------------------------------------------
// K1: exclusive prefix sums of lens + zero stats (4 x 256 floats)
// ---------------------------------------------------------------------------
__global__ __launch_bounds__(512) void scan_zero_kernel(
    const int* __restrict__ slen, const int* __restrict__ dlen,
    int* __restrict__ soff, int* __restrict__ doff,
    float* __restrict__ stats, int B)
{
    __shared__ int ss[512], dd[512];
    const int t = threadIdx.x;
    const int sv = (t < B) ? slen[t] : 0;
    const int dv = (t < B) ? dlen[t] : 0;
    ss[t] = sv; dd[t] = dv;
    __syncthreads();
    for (int o = 1; o < 512; o <<= 1) {
        int a = (t >= o) ? ss[t - o] : 0;
        int b = (t >= o) ? dd[t - o] : 0;
        __syncthreads();
        ss[t] += a; dd[t] += b;
        __syncthreads();
    }
    if (t < B) { soff[t] = ss[t] - sv; doff[t] = dd[t] - dv; }
    stats[t] = 0.f;
    stats[t + 512] = 0.f;
}

// ---------------------------------------------------------------------------
// prepass: [N,256] f32 (f = d*8+h) -> per-head bf16 planes T[h][n][32];
// blockIdx.y==0: src -> KT + d-major VT2[h][32][n]; ==1: dst -> QT.
// ---------------------------------------------------------------------------
__global__ __launch_bounds__(256) void prepass_kernel(
    const float* __restrict__ src, const float* __restrict__ dst,
    unsigned short* __restrict__ KT, unsigned short* __restrict__ VT2,
    unsigned short* __restrict__ QT, int N)
{
    __shared__ unsigned short pl[8 * 64 * 40];   // [h][row][d], stride 40
    const int t = threadIdx.x;
    const int rb = blockIdx.x * 64;
    const int isrc = (blockIdx.y == 0);
    const float* __restrict__ in = isrc ? src : dst;
    unsigned short* __restrict__ T = isrc ? KT : QT;
    #pragma unroll
    for (int i = 0; i < 16; ++i) {
        const int idx = t + i * 256;             // 4096 float4s
        const int row = idx >> 6, f4 = idx & 63;
        const float4 v = ((const float4*)in)[(size_t)(rb + row) * 64 + f4];
        const int f0 = f4 * 4, h0 = f0 & 7, d = f0 >> 3;
        pl[(h0 + 0) * 2560 + row * 40 + d] = f2bf(v.x);
        pl[(h0 + 1) * 2560 + row * 40 + d] = f2bf(v.y);
        pl[(h0 + 2) * 2560 + row * 40 + d] = f2bf(v.z);
        pl[(h0 + 3) * 2560 + row * 40 + d] = f2bf(v.w);
    }
    __syncthreads();
    #pragma unroll
    for (int i = 0; i < 8; ++i) {
        const int idx = t + i * 256;             // 2048 16B chunks
        const int h = idx >> 8, rem = idx & 255, row = rem >> 2, c = rem & 3;
        const bf16x8 val = *(const bf16x8*)&pl[h * 2560 + row * 40 + c * 8];
        *(bf16x8*)&T[(size_t)(h * N + rb + row) * 32 + c * 8] = val;
    }
    if (isrc) {
        #pragma unroll
        for (int i = 0; i < 8; ++i) {
            const int idx = t + i * 256;         // 8 planes x 32 d x 8 n-chunks
            const int h = idx >> 8, rem = idx & 255, d = rem >> 3, nc = rem & 7;
            unsigned short tmp[8];
            #pragma unroll
            for (int j = 0; j < 8; ++j) tmp[j] = pl[h * 2560 + (nc * 8 + j) * 40 + d];
            ushort4 lo, hi;
            lo.x = tmp[0]; lo.y = tmp[1]; lo.z = tmp[2]; lo.w = tmp[3];
            hi.x = tmp[4]; hi.y = tmp[5]; hi.z = tmp[6]; hi.w = tmp[7];
            *(ushort4*)&VT2[(size_t)(h * 32 + d) * N + rb + nc * 8] = lo;
            *(ushort4*)&VT2[(size_t)(h * 32 + d) * N + rb + nc * 8 + 4] = hi;
        }
    }
}

// ---------------------------------------------------------------------------
// weights cvt: W1 with K-permutation (kp = half*256 + h*32 + d), W2 plain.
// ---------------------------------------------------------------------------
__global__ __launch_bounds__(256) void cvtW_kernel(
    const float* __restrict__ W1, const float* __restrict__ W2,
    unsigned short* __restrict__ W1p, unsigned short* __restrict__ W2bf)
{
    const int idx = blockIdx.x * 256 + threadIdx.x;
    if (idx < 131072) {
        const int kp = idx & 511, c = idx >> 9;
        const int half = kp >> 8, r = kp & 255, hh = r >> 5, d = r & 31;
        W1p[(size_t)c * 512 + kp] = f2bf(W1[(size_t)c * 512 + half * 256 + d * 8 + hh]);
    } else {
        const int i2 = idx - 131072;
        W2bf[i2] = f2bf(W2[i2]);
    }
}

// ---------------------------------------------------------------------------
// K2: MFMA attention (one wave per (graph, head)); unchanged from R3.
// ---------------------------------------------------------------------------
template<int LS>
__device__ __forceinline__ void attn_body(
    const unsigned short* __restrict__ KT, const unsigned short* __restrict__ QT,
    const unsigned short* __restrict__ VT2, unsigned short* __restrict__ OT,
    unsigned short* __restrict__ Ps, int N, int so, int df, int Ld, int h, int lane)
{
    constexpr int MT = LS / 16, CH = LS / 32;
    const int lr = lane & 15, lq = lane >> 4;
    const float iscale = 0.17677669529663687f;  // 1/sqrt(32)

    bf16x8 kf[MT];
    #pragma unroll
    for (int mt = 0; mt < MT; ++mt)
        kf[mt] = *(const bf16x8*)&KT[(size_t)(h * N + so + mt * 16 + lr) * 32 + lq * 8];
    bf16x8 vf[CH][2];
    #pragma unroll
    for (int c = 0; c < CH; ++c)
        #pragma unroll
        for (int dt = 0; dt < 2; ++dt)
            vf[c][dt] = *(const bf16x8*)&VT2[(size_t)(h * 32 + dt * 16 + lr) * N + so + c * 32 + lq * 8];

    const int NT = Ld >> 4;
    for (int nt = 0; nt < NT; ++nt) {
        const bf16x8 qf = *(const bf16x8*)&QT[(size_t)(h * N + df + nt * 16 + lr) * 32 + lq * 8];
        f32x4 s[MT];
        #pragma unroll
        for (int mt = 0; mt < MT; ++mt) {
            f32x4 z = {0.f, 0.f, 0.f, 0.f};
            s[mt] = __builtin_amdgcn_mfma_f32_16x16x32_bf16(kf[mt], qf, z, 0, 0, 0);
        }
        float mx = -INFINITY;
        #pragma unroll
        for (int mt = 0; mt < MT; ++mt)
            mx = fmaxf(mx, fmaxf(fmaxf(s[mt][0], s[mt][1]), fmaxf(s[mt][2], s[mt][3])));
        mx = fmaxf(mx, __shfl_xor(mx, 16));
        mx = fmaxf(mx, __shfl_xor(mx, 32));
        const float mxi = mx * iscale;
        float sum = 0.f;
        #pragma unroll
        for (int mt = 0; mt < MT; ++mt) {
            #pragma unroll
            for (int r = 0; r < 4; ++r) {
                const float e = __expf(s[mt][r] * iscale - mxi);
                s[mt][r] = e; sum += e;
            }
        }
        sum += __shfl_xor(sum, 16);
        sum += __shfl_xor(sum, 32);
        const float rinv = 1.f / sum;
        #pragma unroll
        for (int mt = 0; mt < MT; ++mt) {
            uint2 p;
            p.x = ((unsigned)f2bf(s[mt][0])) | (((unsigned)f2bf(s[mt][1])) << 16);
            p.y = ((unsigned)f2bf(s[mt][2])) | (((unsigned)f2bf(s[mt][3])) << 16);
            *(uint2*)&Ps[lr * 136 + mt * 16 + lq * 4] = p;
        }
        __asm__ volatile("" ::: "memory");
        __builtin_amdgcn_wave_barrier();
        f32x4 o0 = {0.f, 0.f, 0.f, 0.f}, o1 = {0.f, 0.f, 0.f, 0.f};
        #pragma unroll
        for (int c = 0; c < CH; ++c) {
            const bf16x8 pa = *(const bf16x8*)&Ps[lr * 136 + c * 32 + lq * 8];
            o0 = __builtin_amdgcn_mfma_f32_16x16x32_bf16(pa, vf[c][0], o0, 0, 0, 0);
            o1 = __builtin_amdgcn_mfma_f32_16x16x32_bf16(pa, vf[c][1], o1, 0, 0, 0);
        }
        __asm__ volatile("" ::: "memory");
        __builtin_amdgcn_wave_barrier();
        #pragma unroll
        for (int r = 0; r < 4; ++r) {
            const float rv = __shfl(rinv, lq * 4 + r);
            const int row = df + nt * 16 + lq * 4 + r;
            OT[(size_t)(h * N + row) * 32 + lr]      = f2bf(o0[r] * rv);
            OT[(size_t)(h * N + row) * 32 + 16 + lr] = f2bf(o1[r] * rv);
        }
    }
}

__global__ __launch_bounds__(256) void attn_mfma(
    const unsigned short* __restrict__ KT, const unsigned short* __restrict__ QT,
    const unsigned short* __restrict__ VT2, unsigned short* __restrict__ OT,
    const int* __restrict__ soff, const int* __restrict__ doff,
    const int* __restrict__ slen, const int* __restrict__ dlen, int N)
{
    __shared__ unsigned short Ps[4][16 * 136];
    const int b = blockIdx.x >> 1, half = blockIdx.x & 1;
    const int w = threadIdx.x >> 6, lane = threadIdx.x & 63;
    const int h = half * 4 + w;
    const int Ls = slen[b], Ld = dlen[b], so = soff[b], df = doff[b];
    switch (Ls) {
        case 32:  attn_body<32> (KT, QT, VT2, OT, Ps[w], N, so, df, Ld, h, lane); break;
        case 64:  attn_body<64> (KT, QT, VT2, OT, Ps[w], N, so, df, Ld, h, lane); break;
        case 96:  attn_body<96> (KT, QT, VT2, OT, Ps[w], N, so, df, Ld, h, lane); break;
        default:  attn_body<128>(KT, QT, VT2, OT, Ps[w], N, so, df, Ld, h, lane); break;
    }
}

// ---------------------------------------------------------------------------
// K3: GEMM1 (MFMA bf16): y1 = [QT|OT] @ W1p^T + b1 -> bf16, fused col stats.
// ---------------------------------------------------------------------------
__global__ __launch_bounds__(256) void gemm1_mfma(
    const unsigned short* __restrict__ QT, const unsigned short* __restrict__ OT,
    const unsigned short* __restrict__ W, const float* __restrict__ bias,
    unsigned short* __restrict__ out, float* __restrict__ sum, float* __restrict__ sq,
    int N)
{
    __shared__ unsigned short Abuf[8 * 512];
    __shared__ unsigned short Bbuf[8 * 512];
    const int tid = threadIdx.x;
    const int w = tid >> 6, lane = tid & 63;
    const int rowBase = blockIdx.y * 128, colBase = blockIdx.x * 128;
    const int lr = lane & 15, lq = lane >> 4;
    const int wm = w >> 1, wn = w & 1;

    f32x4 acc[4][4];
    #pragma unroll
    for (int i = 0; i < 4; ++i)
        #pragma unroll
        for (int j = 0; j < 4; ++j) { f32x4 z = {0.f, 0.f, 0.f, 0.f}; acc[i][j] = z; }

    #pragma unroll
    for (int phase = 0; phase < 2; ++phase) {
        const unsigned short* __restrict__ Ap = phase ? OT : QT;
        const int wOff = phase * 256;
        for (int kb = 0; kb < 256; kb += 32) {
            const int hh = (kb >> 5) + (lq >> 2);
            const int dd = (lq & 3) * 8;
            #pragma unroll
            for (int s = 0; s < 2; ++s) {
                const int sub = 2 * w + s;
                const unsigned short* ga = Ap + (size_t)(hh * N + rowBase + sub * 16 + lr) * 32 + dd;
                gl_lds16(ga, &Abuf[sub * 512]);
                const unsigned short* gb = W + (size_t)(colBase + sub * 16 + lr) * 512 + wOff + kb + lq * 8;
                gl_lds16(gb, &Bbuf[sub * 512]);
            }
            __syncthreads();
            bf16x8 af[4], bf[4];
            #pragma unroll
            for (int i = 0; i < 4; ++i) af[i] = *(const bf16x8*)&Abuf[(wm * 4 + i) * 512 + lane * 8];
            #pragma unroll
            for (int j = 0; j < 4; ++j) bf[j] = *(const bf16x8*)&Bbuf[(wn * 4 + j) * 512 + lane * 8];
            #pragma unroll
            for (int i = 0; i < 4; ++i)
                #pragma unroll
                for (int j = 0; j < 4; ++j)
                    acc[i][j] = __builtin_amdgcn_mfma_f32_16x16x32_bf16(af[i], bf[j], acc[i][j], 0, 0, 0);
            __syncthreads();
        }
    }
    const int col0 = colBase + wn * 64;
    #pragma unroll
    for (int j = 0; j < 4; ++j) {
        const int col = col0 + j * 16 + lr;
        const float bv = bias[col];
        float cs = 0.f, cq = 0.f;
        #pragma unroll
        for (int i = 0; i < 4; ++i) {
            const int row0 = rowBase + wm * 64 + i * 16 + lq * 4;
            #pragma unroll
            for (int r = 0; r < 4; ++r) {
                const float v = acc[i][j][r] + bv;
                cs += v; cq += v * v;
                out[(size_t)(row0 + r) * 256 + col] = f2bf(v);
            }
        }
        cs += __shfl_xor(cs, 16); cs += __shfl_xor(cs, 32);
        cq += __shfl_xor(cq, 16); cq += __shfl_xor(cq, 32);
        if (lq == 0) { atomicAdd(&sum[col], cs); atomicAdd(&sq[col], cq); }
    }
}

// ---------------------------------------------------------------------------
// K5: GEMM2 (MFMA bf16): y2 = a2 @ W2^T + b2 -> bf16, fused col stats.
// ---------------------------------------------------------------------------
__global__ __launch_bounds__(256) void gemm2_mfma(
    const unsigned short* __restrict__ A2,
    const unsigned short* __restrict__ W, const float* __restrict__ bias,
    unsigned short* __restrict__ out, float* __restrict__ sum, float* __restrict__ sq)
{
    __shared__ unsigned short Abuf[8 * 512];
    __shared__ unsigned short Bbuf[8 * 512];
    const int tid = threadIdx.x;
    const int w = tid >> 6, lane = tid & 63;
    const int rowBase = blockIdx.y * 128, colBase = blockIdx.x * 128;
    const int lr = lane & 15, lq = lane >> 4;
    const int wm = w >> 1, wn = w & 1;

    f32x4 acc[4][4];
    #pragma unroll
    for (int i = 0; i < 4; ++i)
        #pragma unroll
        for (int j = 0; j < 4; ++j) { f32x4 z = {0.f, 0.f, 0.f, 0.f}; acc[i][j] = z; }

    for (int kb = 0; kb < 256; kb += 32) {
        #pragma unroll
        for (int s = 0; s < 2; ++s) {
            const int sub = 2 * w + s;
            const unsigned short* ga = A2 + (size_t)(rowBase + sub * 16 + lr) * 256 + kb + lq * 8;
            gl_lds16(ga, &Abuf[sub * 512]);
            const unsigned short* gb = W + (size_t)(colBase + sub * 16 + lr) * 256 + kb + lq * 8;
            gl_lds16(gb, &Bbuf[sub * 512]);
        }
        __syncthreads();
        bf16x8 af[4], bf[4];
        #pragma unroll
        for (int i = 0; i < 4; ++i) af[i] = *(const bf16x8*)&Abuf[(wm * 4 + i) * 512 + lane * 8];
        #pragma unroll
        for (int j = 0; j < 4; ++j) bf[j] = *(const bf16x8*)&Bbuf[(wn * 4 + j) * 512 + lane * 8];
        #pragma unroll
        for (int i = 0; i < 4; ++i)
            #pragma unroll
            for (int j = 0; j < 4; ++j)
                acc[i][j] = __builtin_amdgcn_mfma_f32_16x16x32_bf16(af[i], bf[j], acc[i][j], 0, 0, 0);
        __syncthreads();
    }
    const int col0 = colBase + wn * 64;
    #pragma unroll
    for (int j = 0; j < 4; ++j) {
        const int col = col0 + j * 16 + lr;
        const float bv = bias[col];
        float cs = 0.f, cq = 0.f;
        #pragma unroll
        for (int i = 0; i < 4; ++i) {
            const int row0 = rowBase + wm * 64 + i * 16 + lq * 4;
            #pragma unroll
            for (int r = 0; r < 4; ++r) {
                const float v = acc[i][j][r] + bv;
                cs += v; cq += v * v;
                out[(size_t)(row0 + r) * 256 + col] = f2bf(v);
            }
        }
        cs += __shfl_xor(cs, 16); cs += __shfl_xor(cs, 32);
        cq += __shfl_xor(cq, 16); cq += __shfl_xor(cq, 32);
        if (lq == 0) { atomicAdd(&sum[col], cs); atomicAdd(&sq[col], cq); }
    }
}

// ---------------------------------------------------------------------------
// bnrelu: a2 = bf16(relu(bn1(y1bf))), finalize inlined. 8 elems/thread.
// ---------------------------------------------------------------------------
__global__ __launch_bounds__(256) void bnrelu_kernel(
    const unsigned short* __restrict__ y1,
    const float* __restrict__ sum, const float* __restrict__ sq,
    const float* __restrict__ gamma, const float* __restrict__ beta,
    unsigned short* __restrict__ out, int n8, float invN)
{
    const int i = blockIdx.x * 256 + threadIdx.x;
    if (i >= n8) return;
    const int j0 = (i & 31) * 8;
    const bf16x8 yv = ((const bf16x8*)y1)[i];
    short res[8];
    #pragma unroll
    for (int j = 0; j < 8; ++j) {
        const float mean = sum[j0 + j] * invN;
        const float var  = sq[j0 + j] * invN - mean * mean;
        const float rstd = rsqrtf(var + 1e-5f);
        const float sc = gamma[j0 + j] * rstd;
        const float sh = beta[j0 + j] - mean * sc;
        res[j] = (short)f2bf(fmaxf(bfe2f(yv[j]) * sc + sh, 0.f));
    }
    bf16x8 o;
    #pragma unroll
    for (int j = 0; j < 8; ++j) o[j] = res[j];
    ((bf16x8*)out)[i] = o;
}

// ---------------------------------------------------------------------------
// epilogue: out = dst + bn2(y2bf), finalize inlined. 8 elems/thread.
// ---------------------------------------------------------------------------
__global__ __launch_bounds__(256) void epilogue_kernel(
    const float* __restrict__ dst, const unsigned short* __restrict__ y2,
    const float* __restrict__ sum, const float* __restrict__ sq,
    const float* __restrict__ gamma, const float* __restrict__ beta,
    float* __restrict__ out, int n8, float invN)
{
    const int i = blockIdx.x * 256 + threadIdx.x;
    if (i >= n8) return;
    const int j0 = (i & 31) * 8;
    const bf16x8 yv = ((const bf16x8*)y2)[i];
    const float4 d0 = ((const float4*)dst)[2 * i];
    const float4 d1 = ((const float4*)dst)[2 * i + 1];
    float o[8];
    const float dv[8] = {d0.x, d0.y, d0.z, d0.w, d1.x, d1.y, d1.z, d1.w};
    #pragma unroll
    for (int j = 0; j < 8; ++j) {
        const float mean = sum[j0 + j] * invN;
        const float var  = sq[j0 + j] * invN - mean * mean;
        const float rstd = rsqrtf(var + 1e-5f);
        const float sc = gamma[j0 + j] * rstd;
        const float sh = beta[j0 + j] - mean * sc;
        o[j] = dv[j] + bfe2f(yv[j]) * sc + sh;
    }
    float4 o0, o1;
    o0.x = o[0]; o0.y = o[1]; o0.z = o[2]; o0.w = o[3];
    o1.x = o[4]; o1.y = o[5]; o1.z = o[6]; o1.w = o[7];
    ((float4*)out)[2 * i]     = o0;
    ((float4*)out)[2 * i + 1] = o1;
}

// ---------------------------------------------------------------------------
extern "C" void kernel_launch(void* const* d_in, const int* in_sizes, int n_in,
                              void* d_out, int out_size, void* d_ws, size_t ws_size,
                              hipStream_t stream)
{
    const float* src_h  = (const float*)d_in[0];
    const float* dst_h  = (const float*)d_in[1];
    const int*   slen   = (const int*)d_in[2];
    const int*   dlen   = (const int*)d_in[3];
    const float* W1     = (const float*)d_in[4];
    const float* b1     = (const float*)d_in[5];
    const float* gamma1 = (const float*)d_in[6];
    const float* beta1  = (const float*)d_in[7];
    const float* W2     = (const float*)d_in[8];
    const float* b2     = (const float*)d_in[9];
    const float* gamma2 = (const float*)d_in[10];
    const float* beta2  = (const float*)d_in[11];
    float* out = (float*)d_out;

    const int N = in_sizes[1] / H;     // 40960
    const int B = in_sizes[2];         // 512

    // ---- workspace layout (bytes) ----
    char* base = (char*)d_ws;
    int*   soff   = (int*)(base + 0);            // 2KB
    int*   doff   = (int*)(base + 2048);         // 2KB
    float* stats  = (float*)(base + 4096);       // 4KB: sum1, sq1, sum2, sq2
    unsigned short* W1p  = (unsigned short*)(base + 16384);            // 256KB
    unsigned short* W2bf = (unsigned short*)(base + 16384 + 262144);   // 128KB
    const size_t S = (size_t)N * H * sizeof(unsigned short);           // 21 MB
    char* big = base + (1 << 20);
    unsigned short* KT  = (unsigned short*)(big);
    unsigned short* VT2 = (unsigned short*)(big + S);
    unsigned short* QT  = (unsigned short*)(big + 2 * S);
    unsigned short* OT  = (unsigned short*)(big + 3 * S);
    unsigned short* y1bf = KT;    // reuse after attention
    unsigned short* a2   = VT2;   // reuse after bnrelu input ready
    unsigned short* y2bf = QT;    // reuse after gemm1

    const float invN = 1.0f / (float)N;

    scan_zero_kernel<<<1, 512, 0, stream>>>(slen, dlen, soff, doff, stats, B);

    prepass_kernel<<<dim3(N / 64, 2), 256, 0, stream>>>(src_h, dst_h, KT, VT2, QT, N);
    cvtW_kernel<<<768, 256, 0, stream>>>(W1, W2, W1p, W2bf);

    attn_mfma<<<B * 2, 256, 0, stream>>>(KT, QT, VT2, OT, soff, doff, slen, dlen, N);

    dim3 ggrid(H / 128, N / 128);     // (2, 320)
    gemm1_mfma<<<ggrid, 256, 0, stream>>>(QT, OT, W1p, b1, y1bf, stats + 0, stats + 256, N);

    const int n8 = N * H / 8;
    bnrelu_kernel<<<(n8 + 255) / 256, 256, 0, stream>>>(
        y1bf, stats + 0, stats + 256, gamma1, beta1, a2, n8, invN);

    gemm2_mfma<<<ggrid, 256, 0, stream>>>(a2, W2bf, b2, y2bf, stats + 512, stats + 768);

    epilogue_kernel<<<(n8 + 255) / 256, 256, 0, stream>>>(
        dst_h, y2bf, stats + 512, stats + 768, gamma2, beta2, out, n8, invN);
}